// Round 8
// baseline (94.600 us; speedup 1.0000x reference)
//
#include <hip/hip_runtime.h>

#define DF 256
#define HID 16
#define WB 512          // edge slices (= K1 grid)
#define PBITS 8         // partition = 256 nodes
#define PMAX 512        // max partitions (LDS hist width)

// ---------- K1: hist + global range-reserve + scatter, fused with sval ----------
__global__ void __launch_bounds__(512, 2)
sort_sval_kernel(const float* __restrict__ x, const int* __restrict__ src,
                 const int* __restrict__ dst, const float* __restrict__ Wm,
                 const float* __restrict__ W_fc, unsigned* __restrict__ gcur,
                 unsigned* __restrict__ sorted, float* __restrict__ sv,
                 int N, int E, int P, int Epw, unsigned cap) {
    __shared__ unsigned h[PMAX];   // hist -> then per-partition global cursor
    const int w = blockIdx.x;
    const size_t e0 = (size_t)w * Epw;
    int m = (int)((size_t)E > e0 ? (size_t)E - e0 : 0);
    if (m > Epw) m = Epw;

    for (int p = threadIdx.x; p < P; p += 512) h[p] = 0u;
    __syncthreads();
    // pass 1: histogram of this slice's dst partitions
    for (int i = threadIdx.x; i < m; i += 512)
        atomicAdd(&h[((unsigned)dst[e0 + i]) >> PBITS], 1u);
    __syncthreads();
    // reserve contiguous ranges: one global atomic per nonempty (block, partition)
    for (int p = threadIdx.x; p < P; p += 512) {
        unsigned c = h[p];
        unsigned b = c ? atomicAdd(&gcur[p], c) : 0u;
        h[p] = (unsigned)p * cap + b;   // h becomes the block's write cursor
    }
    __syncthreads();
    // pass 2: scatter edges into reserved slots (run-contiguous per (block,partition))
    for (int i = threadIdx.x; i < m; i += 512) {
        unsigned s = (unsigned)src[e0 + i];
        unsigned d = (unsigned)dst[e0 + i];
        unsigned pp = d >> PBITS;
        unsigned slot = atomicAdd(&h[pp], 1u);
        if (slot < (pp + 1u) * cap)            // capacity guard (never trips at 2x avg)
            sorted[slot] = (s << PBITS) | (d & 255u);
    }

    // fused sval: s[row] = x[row] . (Wm @ W_fc); overlaps x BW with edge latency
    const int lane = threadIdx.x & 63, wid = threadIdx.x >> 6;  // 8 waves
    float a0 = 0.f, a1 = 0.f, a2 = 0.f, a3 = 0.f;
    const float* wrow = Wm + (size_t)(lane * 4) * HID;
#pragma unroll
    for (int j = 0; j < HID; ++j) {
        float f = W_fc[j];
        a0 += wrow[j] * f;
        a1 += wrow[HID + j] * f;
        a2 += wrow[2 * HID + j] * f;
        a3 += wrow[3 * HID + j] * f;
    }
    for (int row = w * 8 + wid; row < N; row += WB * 8) {
        float4 xv = reinterpret_cast<const float4*>(x + (size_t)row * DF)[lane];
        float acc = xv.x * a0 + xv.y * a1 + xv.z * a2 + xv.w * a3;
#pragma unroll
        for (int off = 32; off > 0; off >>= 1) acc += __shfl_xor(acc, off, 64);
        if (lane == 0) sv[row] = acc;
    }
}

// ---------- K2: per-partition degree walk -> dinv, tval ----------
__global__ void __launch_bounds__(1024)
degfin_kernel(const unsigned* __restrict__ sorted, const unsigned* __restrict__ gcur,
              const float* __restrict__ sv, float* __restrict__ dinv,
              float* __restrict__ tval, int N, unsigned cap) {
    __shared__ unsigned dc[256];
    const int p = blockIdx.x;
    if (threadIdx.x < 256) dc[threadIdx.x] = 0u;
    __syncthreads();
    unsigned cnt = gcur[p]; if (cnt > cap) cnt = cap;
    const unsigned* base = sorted + (size_t)p * cap;
    for (unsigned j = threadIdx.x; j < cnt; j += 1024)
        atomicAdd(&dc[base[j] & 255u], 1u);
    __syncthreads();
    if (threadIdx.x < 256) {
        int i = (p << PBITS) + (int)threadIdx.x;
        if (i < N) {
            float deg = 1.0f + (float)dc[threadIdx.x];
            float di = rsqrtf(deg);
            dinv[i] = di;
            tval[i] = sv[i] * di;
        }
    }
}

// ---------- K3: per-partition value walk -> out ----------
__global__ void __launch_bounds__(1024)
reduce_kernel(const unsigned* __restrict__ sorted, const unsigned* __restrict__ gcur,
              const float* __restrict__ tval, const float* __restrict__ dinv,
              const float* __restrict__ sv, const float* __restrict__ b_conv,
              const float* __restrict__ W_fc, const float* __restrict__ b_fc,
              float* __restrict__ out, int N, unsigned cap) {
    __shared__ float facc[256];
    const int p = blockIdx.x;
    if (threadIdx.x < 256) facc[threadIdx.x] = 0.f;
    __syncthreads();
    unsigned cnt = gcur[p]; if (cnt > cap) cnt = cap;
    const unsigned* base = sorted + (size_t)p * cap;
    for (unsigned j = threadIdx.x; j < cnt; j += 1024) {
        unsigned e = base[j];
        atomicAdd(&facc[e & 255u], tval[e >> PBITS]);
    }
    __syncthreads();
    if (threadIdx.x < 256) {
        int i = (p << PBITS) + (int)threadIdx.x;
        if (i < N) {
            float c = 0.f;
#pragma unroll
            for (int j = 0; j < HID; ++j) c += b_conv[j] * W_fc[j];
            float di = dinv[i];
            out[i] = sv[i] * di * di + c + b_fc[0] + di * facc[threadIdx.x];
        }
    }
}

// ---------- fallback: proven global-atomic path ----------
__global__ void fb_sval(const float* __restrict__ x, const float* __restrict__ Wm,
                        const float* __restrict__ W_fc, float* __restrict__ sv, int N) {
    __shared__ float wl[DF];
    int k = threadIdx.x;
    float a = 0.f;
#pragma unroll
    for (int j = 0; j < HID; ++j) a += Wm[k * HID + j] * W_fc[j];
    wl[k] = a;
    __syncthreads();
    int lane = threadIdx.x & 63, wid = threadIdx.x >> 6;
    float4 wv = reinterpret_cast<const float4*>(wl)[lane];
    for (int row = blockIdx.x * 4 + wid; row < N; row += gridDim.x * 4) {
        float4 xv = reinterpret_cast<const float4*>(x + (size_t)row * DF)[lane];
        float acc = xv.x * wv.x + xv.y * wv.y + xv.z * wv.z + xv.w * wv.w;
#pragma unroll
        for (int off = 32; off > 0; off >>= 1) acc += __shfl_xor(acc, off, 64);
        if (lane == 0) sv[row] = acc;
    }
}
__global__ void fb_count(const int* __restrict__ dst, unsigned* __restrict__ cnt, int E) {
    int stride = gridDim.x * blockDim.x;
    for (int e = blockIdx.x * blockDim.x + threadIdx.x; e < E; e += stride)
        atomicAdd(&cnt[dst[e]], 1u);
}
__global__ void fb_node(const unsigned* __restrict__ cnt, const float* __restrict__ sv,
                        const float* __restrict__ b_conv, const float* __restrict__ W_fc,
                        const float* __restrict__ b_fc, float* __restrict__ dinv,
                        float* __restrict__ tval, float* __restrict__ out, int N) {
    int i = blockIdx.x * blockDim.x + threadIdx.x;
    if (i < N) {
        float c = 0.f;
#pragma unroll
        for (int j = 0; j < HID; ++j) c += b_conv[j] * W_fc[j];
        float deg = 1.0f + (float)cnt[i];
        float di = rsqrtf(deg);
        float s = sv[i];
        dinv[i] = di; tval[i] = s * di;
        out[i] = s / deg + c + b_fc[0];
    }
}
__global__ void fb_scatter(const int* __restrict__ src, const int* __restrict__ dst,
                           const float* __restrict__ tval, const float* __restrict__ dinv,
                           float* __restrict__ out, int E) {
    int stride = gridDim.x * blockDim.x;
    for (int e = blockIdx.x * blockDim.x + threadIdx.x; e < E; e += stride) {
        int si = src[e], di = dst[e];
        atomicAdd(&out[di], tval[si] * dinv[di]);
    }
}

extern "C" void kernel_launch(void* const* d_in, const int* in_sizes, int n_in,
                              void* d_out, int out_size, void* d_ws, size_t ws_size,
                              hipStream_t stream) {
    const float* x      = (const float*)d_in[0];
    const int*   ei     = (const int*)d_in[1];
    const float* Wm     = (const float*)d_in[2];
    const float* b_conv = (const float*)d_in[3];
    const float* W_fc   = (const float*)d_in[4];
    const float* b_fc   = (const float*)d_in[5];
    float* out = (float*)d_out;

    const int N = in_sizes[0] / DF;   // 100000
    const int E = in_sizes[1] / 2;    // 3200000
    const int* src = ei;
    const int* dst = ei + E;

    const int P   = (N + 255) >> PBITS;                 // 391
    const int Epw = (E + WB - 1) / WB;                  // 6250
    const unsigned avg = (unsigned)((E + P - 1) / P);   // ~8185
    const unsigned cap = ((2u * avg) + 255u) & ~255u;   // ~16384 (2x avg, vast margin)

    char* ws = (char*)d_ws;
    float* sv   = (float*)ws;                               // N
    float* dinv = sv + N;                                   // N
    float* tval = dinv + N;                                 // N
    unsigned* gcur   = (unsigned*)(tval + N);               // P (pad 512)
    unsigned* sorted = gcur + 512;                          // P*cap

    const size_t need = ((size_t)3 * N + 512 + (size_t)P * cap) * 4;

    if (P >= 1 && P <= PMAX && N <= (1 << 23) && ws_size >= need) {
        hipMemsetAsync(gcur, 0, (size_t)P * 4, stream);
        sort_sval_kernel<<<WB, 512, 0, stream>>>(x, src, dst, Wm, W_fc, gcur, sorted,
                                                 sv, N, E, P, Epw, cap);
        degfin_kernel<<<P, 1024, 0, stream>>>(sorted, gcur, sv, dinv, tval, N, cap);
        reduce_kernel<<<P, 1024, 0, stream>>>(sorted, gcur, tval, dinv, sv,
                                              b_conv, W_fc, b_fc, out, N, cap);
    } else {
        unsigned* fcnt = (unsigned*)(tval + N);
        hipMemsetAsync(fcnt, 0, (size_t)N * 4, stream);
        fb_sval<<<2048, 256, 0, stream>>>(x, Wm, W_fc, sv, N);
        fb_count<<<2048, 256, 0, stream>>>(dst, fcnt, E);
        fb_node<<<(N + 255) / 256, 256, 0, stream>>>(fcnt, sv, b_conv, W_fc, b_fc, dinv, tval, out, N);
        fb_scatter<<<2048, 256, 0, stream>>>(src, dst, tval, dinv, out, E);
    }
}